// Round 5
// baseline (166.113 us; speedup 1.0000x reference)
//
#include <hip/hip_runtime.h>
#include <math.h>

// SpiralNet bf16-MFMA v11: int8 per-row-scaled intermediate tables.
// Model (v8/v10): gather-latency-capped, t ~ lines x L_avg, concurrency at
// the per-CU miss cap. v11 halves BOTH factors on layers 1-2:
//  - h1/h2 stored as i8 [n][64] (64 B/row = ONE cache line, was two) with
//    per-row f32 scale (400 KB arrays, hot). Lines: 6M -> 3.6M.
//  - tables 12.8 -> 6.4 MB -> XCD-L2 hit ~31% -> ~62%, L_avg ~476 -> ~352.
//  - weights stay bf16; gathered i8 is dequantized to bf16 in VALU (4%
//    VALUBusy -> headroom; dequant overlaps in-flight gather latency).
//  - scale is uniform per lane's fragment (lane's row = rg[m]) -> loaded
//    ONCE per wave per layer, no per-gather overhead.
// Producer epilogue: ELU -> per-row absmax (4x shfl_xor width 16) ->
// rne-quantize to i8 + store scale. Layer-0 input table stays bf16.
// Final output: fp32 nontemporal (one-touch stream), as v10.

typedef __bf16 bf16;
typedef bf16  bf16x4 __attribute__((ext_vector_type(4)));
typedef bf16  bf16x8 __attribute__((ext_vector_type(8)));
typedef float f32x4  __attribute__((ext_vector_type(4)));

// Pack W [K][COUT] f32 into fragment-ordered bf16:
// frag f = (s*CC + cc)*NT + t; element lane*8+j of frag f is
// W[k = s*CIN + cc*32 + (lane>>4)*8 + j][col = t*16 + (lane&15)].
template<int CIN, int COUT>
__device__ inline void pack_one(const float* __restrict__ W, bf16* __restrict__ BP, int e) {
    constexpr int NT = COUT / 16, CC = CIN / 32;
    const int f = e >> 9, r = e & 511, lane = r >> 3, j = r & 7;
    const int t = f % NT, cc = (f / NT) % CC, s = f / (NT * CC);
    const int col = t * 16 + (lane & 15);
    const int k   = s * CIN + cc * 32 + (lane >> 4) * 8 + j;
    BP[e] = (bf16)W[k * COUT + col];
}

__global__ __launch_bounds__(256)
void prep_all(const float* __restrict__ x, bf16* __restrict__ xb,
              const float* __restrict__ W0, const float* __restrict__ W1,
              const float* __restrict__ W2, bf16* __restrict__ B0,
              bf16* __restrict__ B1, bf16* __restrict__ B2, int n)
{
    const int gid = blockIdx.x * 256 + threadIdx.x;
    const int e = gid * 4;
    if (e < n * 32) {
        const f32x4 v = *reinterpret_cast<const f32x4*>(x + e);
        bf16x4 o = {(bf16)v[0], (bf16)v[1], (bf16)v[2], (bf16)v[3]};
        *reinterpret_cast<bf16x4*>(xb + e) = o;
    }
    if (gid < 384 * 64)                       pack_one<32, 64>(W0, B0, gid);
    else if (gid < 384 * 64 + 768 * 64)       pack_one<64, 64>(W1, B1, gid - 384 * 64);
    else if (gid < 384 * 64 + 768 * 64 + 768 * 32)
                                              pack_one<64, 32>(W2, B2, gid - 384 * 64 - 768 * 64);
}

// AMODE: 0 = gather bf16 table (stride CIN elems); 1 = gather i8 table
//        (stride CIN bytes) + per-row scale from scin, dequant in VALU.
// OMODE: 1 = store i8 + per-row scale (intermediate); 2 = fp32 nt (final).
template<int CIN, int COUT, bool ELU, int AMODE, int OMODE, typename TOUT>
__global__ __launch_bounds__(256, 5)
void spiral_mfma(const void* __restrict__ hin, const float* __restrict__ scin,
                 const int* __restrict__ idx, const bf16* __restrict__ BP,
                 const float* __restrict__ bias,
                 TOUT* __restrict__ out, float* __restrict__ scout, int n)
{
    constexpr int CC  = CIN / 32;        // 32-k chunks per spiral step (1 or 2)
    constexpr int NT  = COUT / 16;       // 16-col output tiles (2 or 4)
    constexpr int PS  = CIN * COUT;      // B elems per spiral step
    constexpr int SC  = 6 / CC;          // steps/chunk -> batch depth SC*CC = 6
    constexpr int NCH = 12 / SC;         // chunks per layer (2 or 4)
    constexpr int PL  = 6;               // fenced gathers per chunk per wave

    __shared__ bf16 Bs[SC * PS];         // 24 KB (L0/L1), 12 KB (L2)

    const int tid  = threadIdx.x;
    const int lane = tid & 63;
    const int wave = tid >> 6;           // 0..3
    const int m    = lane & 15;
    const int quad = lane >> 4;
    const int i0   = (blockIdx.x * 4 + wave) * 16;   // one 16-row tile/wave
    const bool valid = (i0 < n);                     // n%16==0: all-or-none

    // Gather indices (48B/row, 16B-aligned), clamped for tail waves. Cached:
    // idx re-read by all three layers.
    const int ir = min(i0 + m, n - 1);
    const int4* ip = reinterpret_cast<const int4*>(idx + (size_t)ir * 12);
    const int4 q0 = ip[0], q1 = ip[1], q2 = ip[2];
    const int rg[12] = {q0.x,q0.y,q0.z,q0.w, q1.x,q1.y,q1.z,q1.w, q2.x,q2.y,q2.z,q2.w};

    // Per-row dequant scales: lane's A-fragment always comes from row rg[s]
    // (s keyed by this lane's m) -> one scalar per step, loaded once.
    float sc[12];
    if (AMODE == 1) {
        #pragma unroll
        for (int s = 0; s < 12; ++s) sc[s] = scin[rg[s]];
    }

    f32x4 acc[NT] = {};

    #pragma unroll
    for (int c = 0; c < NCH; ++c) {
        if (c) __syncthreads();          // Bs reuse: consumers done
        // Stage chunk c of packed B into LDS (contiguous 16B copies).
        const bf16* src = BP + (size_t)c * SC * PS;
        #pragma unroll
        for (int r2 = tid; r2 < SC * PS / 8; r2 += 256)
            *reinterpret_cast<bf16x8*>(&Bs[r2 * 8]) =
                *reinterpret_cast<const bf16x8*>(&src[r2 * 8]);
        __syncthreads();

        // ---- fenced batch: 6 independent gathers, then dequant + MFMAs ----
        bf16x8 a[PL];
        if (AMODE == 0) {
            const bf16* h = (const bf16*)hin;
            #pragma unroll
            for (int sl = 0; sl < SC; ++sl)
                #pragma unroll
                for (int cc = 0; cc < CC; ++cc)
                    a[sl * CC + cc] = *reinterpret_cast<const bf16x8*>(
                        h + (size_t)rg[c * SC + sl] * CIN + cc * 32 + quad * 8);
            __builtin_amdgcn_sched_barrier(0);   // all 6 loads issue first
        } else {
            const signed char* h = (const signed char*)hin;
            int2 raw[PL];
            #pragma unroll
            for (int sl = 0; sl < SC; ++sl)
                #pragma unroll
                for (int cc = 0; cc < CC; ++cc)
                    raw[sl * CC + cc] = *reinterpret_cast<const int2*>(
                        h + (size_t)rg[c * SC + sl] * CIN + cc * 32 + quad * 8);
            __builtin_amdgcn_sched_barrier(0);   // all 6 loads issue first
            // Dequant i8 -> bf16 (overlaps remaining in-flight loads).
            #pragma unroll
            for (int sl = 0; sl < SC; ++sl) {
                const float scl = sc[c * SC + sl];
                #pragma unroll
                for (int cc = 0; cc < CC; ++cc) {
                    const int2 r = raw[sl * CC + cc];
                    bf16x8 av;
                    #pragma unroll
                    for (int j = 0; j < 4; ++j) {
                        av[j]     = (bf16)((float)((signed char)((r.x >> (8 * j)) & 0xff)) * scl);
                        av[j + 4] = (bf16)((float)((signed char)((r.y >> (8 * j)) & 0xff)) * scl);
                    }
                    a[sl * CC + cc] = av;
                }
            }
        }
        #pragma unroll
        for (int p = 0; p < PL; ++p)
            #pragma unroll
            for (int t = 0; t < NT; ++t) {
                const bf16x8 b = *reinterpret_cast<const bf16x8*>(
                    &Bs[(p * NT + t) * 512 + lane * 8]);
                acc[t] = __builtin_amdgcn_mfma_f32_16x16x32_bf16(a[p], b, acc[t], 0, 0, 0);
            }
    }

    if (!valid) return;

    // Finalize: bias + activation. D[row = quad*4+g][col = t*16+m].
    float v[NT][4];
    #pragma unroll
    for (int t = 0; t < NT; ++t) {
        const float bv = bias[t * 16 + m];
        #pragma unroll
        for (int g = 0; g < 4; ++g) {
            float x = acc[t][g] + bv;
            if (ELU) x = (x > 0.f) ? x : (__expf(x) - 1.f);
            v[t][g] = x;
        }
    }

    if (OMODE == 2) {
        // Final layer: fp32 nontemporal (pure one-touch stream).
        #pragma unroll
        for (int t = 0; t < NT; ++t)
            #pragma unroll
            for (int g = 0; g < 4; ++g)
                __builtin_nontemporal_store((TOUT)v[t][g],
                    out + (size_t)(i0 + quad * 4 + g) * COUT + t * 16 + m);
    } else {
        // Intermediate: per-row absmax -> i8 quantize + store scale.
        // Row (quad,g) lives in this quad's 16 lanes x NT t-values.
        #pragma unroll
        for (int g = 0; g < 4; ++g) {
            float mx = 0.f;
            #pragma unroll
            for (int t = 0; t < NT; ++t) mx = fmaxf(mx, fabsf(v[t][g]));
            #pragma unroll
            for (int d = 1; d < 16; d <<= 1)
                mx = fmaxf(mx, __shfl_xor(mx, d, 16));
            const float qs = (mx > 0.f) ? 127.f / mx : 0.f;
            const int row = i0 + quad * 4 + g;
            #pragma unroll
            for (int t = 0; t < NT; ++t) {
                const int q = (int)rintf(v[t][g] * qs);
                out[(size_t)row * COUT + t * 16 + m] = (TOUT)q;
            }
            if (m == 0) scout[row] = (mx > 0.f) ? mx / 127.f : 0.f;
        }
    }
}

extern "C" void kernel_launch(void* const* d_in, const int* in_sizes, int n_in,
                              void* d_out, int out_size, void* d_ws, size_t ws_size,
                              hipStream_t stream) {
    const float* x   = (const float*)d_in[0];   // [N,32] fp32
    const int*   idx = (const int*)d_in[1];     // [N,12]
    const float* W0  = (const float*)d_in[2];   // [384,64]
    const float* b0  = (const float*)d_in[3];
    const float* W1  = (const float*)d_in[4];   // [768,64]
    const float* b1  = (const float*)d_in[5];
    const float* W2  = (const float*)d_in[6];   // [768,32]
    const float* b2  = (const float*)d_in[7];
    float* out = (float*)d_out;                 // [N,32] fp32

    const int n = in_sizes[0] / 32;             // N = 100000

    // Workspace (all offsets multiples of 16 B for vector loads; n%16==0):
    bf16*        xb = (bf16*)d_ws;                          // [n,32] bf16
    signed char* h1 = (signed char*)(xb + (size_t)n * 32);  // [n,64] i8
    signed char* h2 = h1 + (size_t)n * 64;                  // [n,64] i8
    float*       s1 = (float*)(h2 + (size_t)n * 64);        // [n] scales
    float*       s2 = s1 + n;                               // [n] scales
    bf16*        B0 = (bf16*)(s2 + n);                      // 384*64
    bf16*        B1 = B0 + 384 * 64;                        // 768*64
    bf16*        B2 = B1 + 768 * 64;                        // 768*32

    const int prep_threads = n * 8;             // covers n*32/4 cvt + 98304 pack
    prep_all<<<(prep_threads + 255) / 256, dim3(256), 0, stream>>>(x, xb, W0, W1, W2, B0, B1, B2, n);

    const int grid = (n + 63) / 64;             // 4 waves x 16 rows per block
    spiral_mfma<32, 64, true,  0, 1, signed char><<<grid, dim3(256), 0, stream>>>(
        xb, nullptr, idx, B0, b0, h1, s1, n);
    spiral_mfma<64, 64, true,  1, 1, signed char><<<grid, dim3(256), 0, stream>>>(
        h1, s1, idx, B1, b1, h2, s2, n);
    spiral_mfma<64, 32, false, 1, 2, float      ><<<grid, dim3(256), 0, stream>>>(
        h2, s2, idx, B2, b2, out, nullptr, n);
}